// Round 8
// baseline (386.327 us; speedup 1.0000x reference)
//
#include <hip/hip_runtime.h>
#include <hip/hip_bf16.h>
#include <stdint.h>

#define B_ 2
#define D_ 128
#define H_ 512
#define W_ 512
#define G_ 60
#define NQ_ 7200
#define BORDER_ 16
#define STEP_ 8

typedef __attribute__((ext_vector_type(8))) short short8;
typedef __attribute__((ext_vector_type(4))) float f32x4;
typedef __attribute__((ext_vector_type(4))) uint32_t u32x4;

__device__ __forceinline__ float bf_lo(uint32_t u){ return __builtin_bit_cast(float, u << 16); }
__device__ __forceinline__ float bf_hi(uint32_t u){ return __builtin_bit_cast(float, u & 0xffff0000u); }

__device__ __forceinline__ uint32_t pack2bf(float lo, float hi){
  uint16_t l = __builtin_bit_cast(uint16_t, __float2bfloat16(lo));
  uint16_t h = __builtin_bit_cast(uint16_t, __float2bfloat16(hi));
  return (uint32_t)l | ((uint32_t)h << 16);
}

// ---------------- gt region zero-fill (aligned full-line nt float4 stream) ----------------
__global__ __launch_bounds__(256) void gtzero_k(f32x4* __restrict__ gt, size_t n4){
  size_t i = (size_t)blockIdx.x * 256 + threadIdx.x;
  size_t stride = (size_t)gridDim.x * 256;
  f32x4 z = {0.f, 0.f, 0.f, 0.f};
  for (; i < n4; i += stride)
    __builtin_nontemporal_store(z, gt + i);
}

// ---------------- feat2 (B,D,H,W) f32 -> (B,H,W,D) bf16 ----------------
__global__ __launch_bounds__(256) void transpose_k(const float* __restrict__ src,
                                                   __hip_bfloat16* __restrict__ dst){
  __shared__ uint32_t lds2[64][65];
  int b = blockIdx.z, y = blockIdx.y, x0 = blockIdx.x * 64;
  int tid = threadIdx.x;
  size_t plane = (size_t)H_ * W_;

  int xq = tid & 15;        // x-quad (4 floats)
  int eg = tid >> 4;        // 0..15
  size_t base_in = (((size_t)b * D_) * H_ + y) * W_ + x0 + 4 * xq;
  #pragma unroll
  for (int it = 0; it < 4; ++it){
    int e = eg + 16 * it;   // d-pair 0..63
    f32x4 lo = __builtin_nontemporal_load(
        reinterpret_cast<const f32x4*>(src + base_in + (size_t)(2 * e) * plane));
    f32x4 hi = __builtin_nontemporal_load(
        reinterpret_cast<const f32x4*>(src + base_in + (size_t)(2 * e + 1) * plane));
    lds2[e][4 * xq + 0] = pack2bf(lo[0], hi[0]);
    lds2[e][4 * xq + 1] = pack2bf(lo[1], hi[1]);
    lds2[e][4 * xq + 2] = pack2bf(lo[2], hi[2]);
    lds2[e][4 * xq + 3] = pack2bf(lo[3], hi[3]);
  }
  __syncthreads();

  int eq = tid & 15;        // u32-quad within a pixel's 64-u32 row
  int xb = tid >> 4;        // 0..15
  size_t pixbase = (((size_t)b * H_ + y) * W_ + x0);
  #pragma unroll
  for (int it = 0; it < 4; ++it){
    int x = xb + 16 * it;
    u32x4 v;
    v[0] = lds2[4 * eq + 0][x];
    v[1] = lds2[4 * eq + 1][x];
    v[2] = lds2[4 * eq + 2][x];
    v[3] = lds2[4 * eq + 3][x];
    *reinterpret_cast<u32x4*>(dst + (pixbase + x) * D_ + 8 * eq) = v;
  }
}

// ---------------- per-query prep: f1, d3, xy tables, mask, qconf ----------------
template<bool USE_T>
__global__ __launch_bounds__(128) void prep_k(
    const float* __restrict__ feat1, const float* __restrict__ feat2,
    const __hip_bfloat16* __restrict__ f2t,
    const float* __restrict__ conf1, const float* __restrict__ aflow,
    __hip_bfloat16* __restrict__ f1o, __hip_bfloat16* __restrict__ d3o,
    float2* __restrict__ qxy, float2* __restrict__ dxy,
    float* __restrict__ omask, float* __restrict__ oqconf)
{
  int n = blockIdx.x;
  int b = n / (G_ * G_); int r = n % (G_ * G_);
  int iy = r / G_, ix = r % G_;
  int y1 = BORDER_ + iy * STEP_, x1 = BORDER_ + ix * STEP_;
  int tid = threadIdx.x;
  size_t pix = ((size_t)b * H_ + y1) * W_ + x1;
  if (tid < 64){
    int d = tid * 2;
    size_t o = (((size_t)b * D_ + d) * H_ + y1) * W_ + x1;
    float lo = feat1[o];
    float hi = feat1[o + (size_t)H_ * W_];
    *reinterpret_cast<uint32_t*>(f1o + (size_t)n * D_ + d) = pack2bf(lo, hi);
    if (tid == 0){
      float ax = aflow[(((size_t)b * 2 + 0) * H_ + y1) * W_ + x1];
      float ay = aflow[(((size_t)b * 2 + 1) * H_ + y1) * W_ + x1];
      int x2 = (int)(ax + 0.5f);   // trunc toward zero == astype(int32)
      int y2 = (int)(ay + 0.5f);
      omask[n] = (x2 >= 0 && y2 >= 0 && x2 < W_ && y2 < H_) ? 1.0f : 0.0f;
      oqconf[n] = conf1[pix];
      float bs = 512.0f * (float)b;
      qxy[n] = make_float2((float)x2 + bs, (float)y2 + bs);
      dxy[n] = make_float2((float)x1 + bs, (float)y1 + bs);
    }
  } else {
    int d = (tid - 64) * 2;
    uint32_t u;
    if (USE_T){
      u = *reinterpret_cast<const uint32_t*>(f2t + pix * D_ + d);
    } else {
      size_t o = (((size_t)b * D_ + d) * H_ + y1) * W_ + x1;
      u = pack2bf(feat2[o], feat2[o + (size_t)H_ * W_]);
    }
    *reinterpret_cast<uint32_t*>(d3o + (size_t)n * D_ + d) = u;
  }
}

// ---------------- pos/neg neighbor scores + gt cols 0..P+NN-1 ----------------
template<bool USE_T>
__global__ __launch_bounds__(256) void posneg_k(
    const __hip_bfloat16* __restrict__ f1o,
    const __hip_bfloat16* __restrict__ f2t,
    const float* __restrict__ feat2,
    const float* __restrict__ aflow,
    const int* __restrict__ pos, const int* __restrict__ neg,
    int P, int NN, float* __restrict__ out, int NCOL, size_t GTOFF)
{
  int n = blockIdx.x;
  int b = n / (G_ * G_); int r = n % (G_ * G_);
  int iy = r / G_, ix = r % G_;
  int y1 = BORDER_ + iy * STEP_, x1 = BORDER_ + ix * STEP_;
  int tid = threadIdx.x;
  int l16 = tid & 15, grp = tid >> 4;

  const uint4 av = *reinterpret_cast<const uint4*>(f1o + (size_t)n * D_ + l16 * 8);
  float a[8];
  a[0] = bf_lo(av.x); a[1] = bf_hi(av.x); a[2] = bf_lo(av.y); a[3] = bf_hi(av.y);
  a[4] = bf_lo(av.z); a[5] = bf_hi(av.z); a[6] = bf_lo(av.w); a[7] = bf_hi(av.w);

  float ax = aflow[(((size_t)b * 2 + 0) * H_ + y1) * W_ + x1];
  float ay = aflow[(((size_t)b * 2 + 1) * H_ + y1) * W_ + x1];
  int x2 = (int)(ax + 0.5f), y2 = (int)(ay + 0.5f);

  int NP = P + NN;
  for (int p0 = 0; p0 < NP; p0 += 16){
    int p = p0 + grp;
    float s = 0.0f;
    if (p < NP){
      int ox, oy;
      if (p < P){ ox = pos[p]; oy = pos[P + p]; }
      else      { ox = neg[p - P]; oy = neg[NN + p - P]; }
      int px = min(max(x2 + ox, 0), W_ - 1);
      int py = min(max(y2 + oy, 0), H_ - 1);
      if (USE_T){
        const uint4 v = *reinterpret_cast<const uint4*>(
            f2t + (((size_t)b * H_ + py) * W_ + px) * D_ + l16 * 8);
        s = a[0]*bf_lo(v.x) + a[1]*bf_hi(v.x) + a[2]*bf_lo(v.y) + a[3]*bf_hi(v.y)
          + a[4]*bf_lo(v.z) + a[5]*bf_hi(v.z) + a[6]*bf_lo(v.w) + a[7]*bf_hi(v.w);
      } else {
        size_t o = (((size_t)b * D_ + l16 * 8) * H_ + py) * W_ + px;
        #pragma unroll
        for (int j = 0; j < 8; ++j) s += a[j] * feat2[o + (size_t)j * H_ * W_];
      }
    }
    s += __shfl_xor(s, 1); s += __shfl_xor(s, 2);
    s += __shfl_xor(s, 4); s += __shfl_xor(s, 8);
    if (p < NP && l16 == 0){
      size_t idx = (size_t)n * NCOL + p;
      out[idx] = s;
      out[GTOFF + idx] = (p < P) ? 1.0f : 0.0f;   // gt zeroed by gtzero_k before
    }
  }
}

// ---- dscores GEMM, row-stripe blocks: 16 rows x full 7200-col span ----
// Per block: A-frags (16 rows of f1o) in registers for the whole kernel;
// loop 29 column-chunks of <=256: MFMA -> LDS stage -> drain each row as
// aligned full-wave bursts. Each output row is ONE sequential 29KB stream,
// chunk-boundary partial lines complete within the same block/L2.
__global__ __launch_bounds__(256) void gemm_k(
    const __hip_bfloat16* __restrict__ f1o, const __hip_bfloat16* __restrict__ d3o,
    const float2* __restrict__ qxy, const float2* __restrict__ dxy,
    float* __restrict__ out, int NCOL, int CB)
{
  __shared__ float sT[16][264];   // stride 264: 16B-aligned rows, 2-way banks max
  int m0 = blockIdx.x * 16;
  int tid = threadIdx.x;
  int lane = tid & 63, wid = tid >> 6;
  int r16 = lane & 15, kg = lane >> 4;
  int wbase = wid * 64;

  // A fragments: 16 rows x K=128, resident in 16 VGPRs x4
  short8 af[4];
  #pragma unroll
  for (int ks = 0; ks < 4; ++ks)
    af[ks] = *reinterpret_cast<const short8*>(
        f1o + (size_t)(m0 + r16) * D_ + ks * 32 + kg * 8);

  for (int cn0 = 0; cn0 < NQ_; cn0 += 256){
    int nc = NQ_ - cn0; if (nc > 256) nc = 256;

    f32x4 acc[4] = {};
    #pragma unroll
    for (int j = 0; j < 4; ++j){
      if (wbase + j * 16 < nc){          // wave-uniform guard
        int nn = cn0 + wbase + j * 16 + r16;
        #pragma unroll
        for (int ks = 0; ks < 4; ++ks){
          short8 br = *reinterpret_cast<const short8*>(
              d3o + (size_t)nn * D_ + ks * 32 + kg * 8);
          acc[j] = __builtin_amdgcn_mfma_f32_16x16x32_bf16(br, af[ks], acc[j], 0, 0, 0);
        }
      }
    }

    // stage: lane holds rows r16, cols wbase + j*16 + kg*4 + t
    #pragma unroll
    for (int j = 0; j < 4; ++j)
      if (wbase + j * 16 < nc)
        *reinterpret_cast<f32x4*>(&sT[r16][wbase + j * 16 + kg * 4]) = acc[j];
    __syncthreads();

    // drain: wave wid handles rows wid*4 .. wid*4+3
    #pragma unroll
    for (int k = 0; k < 4; ++k){
      int r = wid * 4 + k;
      int m = m0 + r;
      float2 q = qxy[m];
      size_t S = (size_t)m * NCOL + CB + cn0;   // dword offset of this row-chunk
      int skip = (int)((16 - (S & 15)) & 15);   // dwords to 64B boundary
      if (lane < skip && lane < nc){            // head (partial line, cached)
        int c = lane;
        float2 dc = dxy[cn0 + c];
        float ddx = q.x - dc.x, ddy = q.y - dc.y;
        out[S + c] = (ddx * ddx + ddy * ddy < 16.0f) ? 0.0f : sT[r][c];
      }
      for (int b = 0; skip + b * 64 < nc; ++b){ // aligned main bursts
        int c = skip + b * 64 + lane;
        if (c < nc){
          float2 dc = dxy[cn0 + c];
          float ddx = q.x - dc.x, ddy = q.y - dc.y;
          out[S + c] = (ddx * ddx + ddy * ddy < 16.0f) ? 0.0f : sT[r][c];
        }
      }
    }
    __syncthreads();
  }
}

extern "C" void kernel_launch(void* const* d_in, const int* in_sizes, int n_in,
                              void* d_out, int out_size, void* d_ws, size_t ws_size,
                              hipStream_t stream)
{
  const float* feat1 = (const float*)d_in[0];
  const float* feat2 = (const float*)d_in[1];
  const float* conf1 = (const float*)d_in[2];
  const float* aflow = (const float*)d_in[4];
  const int* pos = (const int*)d_in[5];
  const int* neg = (const int*)d_in[6];
  int P = in_sizes[5] / 2, NN = in_sizes[6] / 2;
  int NCOL = P + NN + NQ_;
  size_t GTOFF = (size_t)NQ_ * (size_t)NCOL;
  float* out = (float*)d_out;

  char* ws = (char*)d_ws;
  __hip_bfloat16* f1o = (__hip_bfloat16*)ws;                     // 1,843,200 B
  __hip_bfloat16* d3o = (__hip_bfloat16*)(ws + 1843200);         // 1,843,200 B
  float2* qxy = (float2*)(ws + 3686400);                         // 57,600 B
  float2* dxy = (float2*)(ws + 3744000);                         // 57,600 B
  __hip_bfloat16* f2t = (__hip_bfloat16*)(ws + 3801600);         // 134,217,728 B
  size_t needT = 3801600ull + (size_t)B_ * H_ * W_ * D_ * 2;
  bool useT = ws_size >= needT;

  float* omask  = out + 2 * GTOFF;
  float* oqconf = omask + NQ_;

  // zero the full gt region (posneg then writes cols 0..P+NN-1)
  gtzero_k<<<2048, 256, 0, stream>>>((f32x4*)(out + GTOFF), GTOFF / 4);

  if (useT){
    transpose_k<<<dim3(W_ / 64, H_, B_), 256, 0, stream>>>(feat2, f2t);
    prep_k<true><<<NQ_, 128, 0, stream>>>(feat1, feat2, f2t, conf1, aflow,
                                          f1o, d3o, qxy, dxy, omask, oqconf);
    posneg_k<true><<<NQ_, 256, 0, stream>>>(f1o, f2t, feat2, aflow, pos, neg,
                                            P, NN, out, NCOL, GTOFF);
  } else {
    prep_k<false><<<NQ_, 128, 0, stream>>>(feat1, feat2, f2t, conf1, aflow,
                                           f1o, d3o, qxy, dxy, omask, oqconf);
    posneg_k<false><<<NQ_, 256, 0, stream>>>(f1o, f2t, feat2, aflow, pos, neg,
                                             P, NN, out, NCOL, GTOFF);
  }
  gemm_k<<<NQ_ / 16, 256, 0, stream>>>(f1o, d3o, qxy, dxy, out, NCOL, P + NN);
}

// Round 9
// 341.703 us; speedup vs baseline: 1.1306x; 1.1306x over previous
//
#include <hip/hip_runtime.h>
#include <hip/hip_bf16.h>
#include <stdint.h>

#define B_ 2
#define D_ 128
#define H_ 512
#define W_ 512
#define G_ 60
#define NQ_ 7200
#define BORDER_ 16
#define STEP_ 8
#define SEG_ 1800   // columns per gemm block (4 segments x 1800 = 7200)

typedef __attribute__((ext_vector_type(8))) short short8;
typedef __attribute__((ext_vector_type(4))) float f32x4;
typedef __attribute__((ext_vector_type(4))) uint32_t u32x4;

__device__ __forceinline__ float bf_lo(uint32_t u){ return __builtin_bit_cast(float, u << 16); }
__device__ __forceinline__ float bf_hi(uint32_t u){ return __builtin_bit_cast(float, u & 0xffff0000u); }

__device__ __forceinline__ uint32_t pack2bf(float lo, float hi){
  uint16_t l = __builtin_bit_cast(uint16_t, __float2bfloat16(lo));
  uint16_t h = __builtin_bit_cast(uint16_t, __float2bfloat16(hi));
  return (uint32_t)l | ((uint32_t)h << 16);
}

// ---------------- gt region zero-fill (aligned full-line nt float4 stream) ----------------
__global__ __launch_bounds__(256) void gtzero_k(f32x4* __restrict__ gt, size_t n4){
  size_t i = (size_t)blockIdx.x * 256 + threadIdx.x;
  size_t stride = (size_t)gridDim.x * 256;
  f32x4 z = {0.f, 0.f, 0.f, 0.f};
  for (; i < n4; i += stride)
    __builtin_nontemporal_store(z, gt + i);
}

// ---------------- feat2 (B,D,H,W) f32 -> (B,H,W,D) bf16 ----------------
__global__ __launch_bounds__(256) void transpose_k(const float* __restrict__ src,
                                                   __hip_bfloat16* __restrict__ dst){
  __shared__ uint32_t lds2[64][65];
  int b = blockIdx.z, y = blockIdx.y, x0 = blockIdx.x * 64;
  int tid = threadIdx.x;
  size_t plane = (size_t)H_ * W_;

  int xq = tid & 15;        // x-quad (4 floats)
  int eg = tid >> 4;        // 0..15
  size_t base_in = (((size_t)b * D_) * H_ + y) * W_ + x0 + 4 * xq;
  #pragma unroll
  for (int it = 0; it < 4; ++it){
    int e = eg + 16 * it;   // d-pair 0..63
    f32x4 lo = __builtin_nontemporal_load(
        reinterpret_cast<const f32x4*>(src + base_in + (size_t)(2 * e) * plane));
    f32x4 hi = __builtin_nontemporal_load(
        reinterpret_cast<const f32x4*>(src + base_in + (size_t)(2 * e + 1) * plane));
    lds2[e][4 * xq + 0] = pack2bf(lo[0], hi[0]);
    lds2[e][4 * xq + 1] = pack2bf(lo[1], hi[1]);
    lds2[e][4 * xq + 2] = pack2bf(lo[2], hi[2]);
    lds2[e][4 * xq + 3] = pack2bf(lo[3], hi[3]);
  }
  __syncthreads();

  int eq = tid & 15;        // u32-quad within a pixel's 64-u32 row
  int xb = tid >> 4;        // 0..15
  size_t pixbase = (((size_t)b * H_ + y) * W_ + x0);
  #pragma unroll
  for (int it = 0; it < 4; ++it){
    int x = xb + 16 * it;
    u32x4 v;
    v[0] = lds2[4 * eq + 0][x];
    v[1] = lds2[4 * eq + 1][x];
    v[2] = lds2[4 * eq + 2][x];
    v[3] = lds2[4 * eq + 3][x];
    *reinterpret_cast<u32x4*>(dst + (pixbase + x) * D_ + 8 * eq) = v;
  }
}

// ---------------- per-query prep: f1, d3, xy tables, mask, qconf ----------------
template<bool USE_T>
__global__ __launch_bounds__(128) void prep_k(
    const float* __restrict__ feat1, const float* __restrict__ feat2,
    const __hip_bfloat16* __restrict__ f2t,
    const float* __restrict__ conf1, const float* __restrict__ aflow,
    __hip_bfloat16* __restrict__ f1o, __hip_bfloat16* __restrict__ d3o,
    float2* __restrict__ qxy, float2* __restrict__ dxy,
    float* __restrict__ omask, float* __restrict__ oqconf)
{
  int n = blockIdx.x;
  int b = n / (G_ * G_); int r = n % (G_ * G_);
  int iy = r / G_, ix = r % G_;
  int y1 = BORDER_ + iy * STEP_, x1 = BORDER_ + ix * STEP_;
  int tid = threadIdx.x;
  size_t pix = ((size_t)b * H_ + y1) * W_ + x1;
  if (tid < 64){
    int d = tid * 2;
    size_t o = (((size_t)b * D_ + d) * H_ + y1) * W_ + x1;
    float lo = feat1[o];
    float hi = feat1[o + (size_t)H_ * W_];
    *reinterpret_cast<uint32_t*>(f1o + (size_t)n * D_ + d) = pack2bf(lo, hi);
    if (tid == 0){
      float ax = aflow[(((size_t)b * 2 + 0) * H_ + y1) * W_ + x1];
      float ay = aflow[(((size_t)b * 2 + 1) * H_ + y1) * W_ + x1];
      int x2 = (int)(ax + 0.5f);   // trunc toward zero == astype(int32)
      int y2 = (int)(ay + 0.5f);
      omask[n] = (x2 >= 0 && y2 >= 0 && x2 < W_ && y2 < H_) ? 1.0f : 0.0f;
      oqconf[n] = conf1[pix];
      float bs = 512.0f * (float)b;
      qxy[n] = make_float2((float)x2 + bs, (float)y2 + bs);
      dxy[n] = make_float2((float)x1 + bs, (float)y1 + bs);
    }
  } else {
    int d = (tid - 64) * 2;
    uint32_t u;
    if (USE_T){
      u = *reinterpret_cast<const uint32_t*>(f2t + pix * D_ + d);
    } else {
      size_t o = (((size_t)b * D_ + d) * H_ + y1) * W_ + x1;
      u = pack2bf(feat2[o], feat2[o + (size_t)H_ * W_]);
    }
    *reinterpret_cast<uint32_t*>(d3o + (size_t)n * D_ + d) = u;
  }
}

// ---------------- pos/neg neighbor scores + gt cols 0..P+NN-1 ----------------
template<bool USE_T>
__global__ __launch_bounds__(256) void posneg_k(
    const __hip_bfloat16* __restrict__ f1o,
    const __hip_bfloat16* __restrict__ f2t,
    const float* __restrict__ feat2,
    const float* __restrict__ aflow,
    const int* __restrict__ pos, const int* __restrict__ neg,
    int P, int NN, float* __restrict__ out, int NCOL, size_t GTOFF)
{
  int n = blockIdx.x;
  int b = n / (G_ * G_); int r = n % (G_ * G_);
  int iy = r / G_, ix = r % G_;
  int y1 = BORDER_ + iy * STEP_, x1 = BORDER_ + ix * STEP_;
  int tid = threadIdx.x;
  int l16 = tid & 15, grp = tid >> 4;

  const uint4 av = *reinterpret_cast<const uint4*>(f1o + (size_t)n * D_ + l16 * 8);
  float a[8];
  a[0] = bf_lo(av.x); a[1] = bf_hi(av.x); a[2] = bf_lo(av.y); a[3] = bf_hi(av.y);
  a[4] = bf_lo(av.z); a[5] = bf_hi(av.z); a[6] = bf_lo(av.w); a[7] = bf_hi(av.w);

  float ax = aflow[(((size_t)b * 2 + 0) * H_ + y1) * W_ + x1];
  float ay = aflow[(((size_t)b * 2 + 1) * H_ + y1) * W_ + x1];
  int x2 = (int)(ax + 0.5f), y2 = (int)(ay + 0.5f);

  int NP = P + NN;
  for (int p0 = 0; p0 < NP; p0 += 16){
    int p = p0 + grp;
    float s = 0.0f;
    if (p < NP){
      int ox, oy;
      if (p < P){ ox = pos[p]; oy = pos[P + p]; }
      else      { ox = neg[p - P]; oy = neg[NN + p - P]; }
      int px = min(max(x2 + ox, 0), W_ - 1);
      int py = min(max(y2 + oy, 0), H_ - 1);
      if (USE_T){
        const uint4 v = *reinterpret_cast<const uint4*>(
            f2t + (((size_t)b * H_ + py) * W_ + px) * D_ + l16 * 8);
        s = a[0]*bf_lo(v.x) + a[1]*bf_hi(v.x) + a[2]*bf_lo(v.y) + a[3]*bf_hi(v.y)
          + a[4]*bf_lo(v.z) + a[5]*bf_hi(v.z) + a[6]*bf_lo(v.w) + a[7]*bf_hi(v.w);
      } else {
        size_t o = (((size_t)b * D_ + l16 * 8) * H_ + py) * W_ + px;
        #pragma unroll
        for (int j = 0; j < 8; ++j) s += a[j] * feat2[o + (size_t)j * H_ * W_];
      }
    }
    s += __shfl_xor(s, 1); s += __shfl_xor(s, 2);
    s += __shfl_xor(s, 4); s += __shfl_xor(s, 8);
    if (p < NP && l16 == 0){
      size_t idx = (size_t)n * NCOL + p;
      out[idx] = s;
      out[GTOFF + idx] = (p < P) ? 1.0f : 0.0f;   // gt zeroed by gtzero_k before
    }
  }
}

// ---- dscores GEMM, row-stripe x col-segment blocks: 16 rows x 1800 cols ----
// R8's traffic-perfect structure (FETCH 8.4MB, WRITE 203MB) with 4x the
// blocks: grid (450,4). Per-row output is a sequential 7.2KB stream per
// block; chunk-boundary partial lines complete within the same block/L2.
__global__ __launch_bounds__(256) void gemm_k(
    const __hip_bfloat16* __restrict__ f1o, const __hip_bfloat16* __restrict__ d3o,
    const float2* __restrict__ qxy, const float2* __restrict__ dxy,
    float* __restrict__ out, int NCOL, int CB)
{
  __shared__ float sT[16][264];
  int m0 = blockIdx.x * 16;
  int seg0 = blockIdx.y * SEG_;
  int tid = threadIdx.x;
  int lane = tid & 63, wid = tid >> 6;
  int r16 = lane & 15, kg = lane >> 4;
  int wbase = wid * 64;

  // A fragments: 16 rows x K=128, resident in registers for the whole block
  short8 af[4];
  #pragma unroll
  for (int ks = 0; ks < 4; ++ks)
    af[ks] = *reinterpret_cast<const short8*>(
        f1o + (size_t)(m0 + r16) * D_ + ks * 32 + kg * 8);

  for (int cn0 = seg0; cn0 < seg0 + SEG_; cn0 += 256){
    int nc = seg0 + SEG_ - cn0; if (nc > 256) nc = 256;

    f32x4 acc[4] = {};
    #pragma unroll
    for (int j = 0; j < 4; ++j){
      if (wbase + j * 16 < nc){          // wave-uniform guard
        int nn = cn0 + wbase + j * 16 + r16;
        #pragma unroll
        for (int ks = 0; ks < 4; ++ks){
          short8 br = *reinterpret_cast<const short8*>(
              d3o + (size_t)nn * D_ + ks * 32 + kg * 8);
          acc[j] = __builtin_amdgcn_mfma_f32_16x16x32_bf16(br, af[ks], acc[j], 0, 0, 0);
        }
      }
    }

    // stage: lane holds rows r16, cols wbase + j*16 + kg*4 + t
    #pragma unroll
    for (int j = 0; j < 4; ++j)
      if (wbase + j * 16 < nc)
        *reinterpret_cast<f32x4*>(&sT[r16][wbase + j * 16 + kg * 4]) = acc[j];
    __syncthreads();

    // drain: wave wid handles rows wid*4 .. wid*4+3
    #pragma unroll
    for (int k = 0; k < 4; ++k){
      int r = wid * 4 + k;
      int m = m0 + r;
      float2 q = qxy[m];
      size_t S = (size_t)m * NCOL + CB + cn0;   // dword offset of this row-chunk
      int skip = (int)((16 - (S & 15)) & 15);   // dwords to 64B boundary
      if (lane < skip && lane < nc){            // head (partial line, cached)
        int c = lane;
        float2 dc = dxy[cn0 + c];
        float ddx = q.x - dc.x, ddy = q.y - dc.y;
        out[S + c] = (ddx * ddx + ddy * ddy < 16.0f) ? 0.0f : sT[r][c];
      }
      for (int b = 0; skip + b * 64 < nc; ++b){ // aligned main bursts
        int c = skip + b * 64 + lane;
        if (c < nc){
          float2 dc = dxy[cn0 + c];
          float ddx = q.x - dc.x, ddy = q.y - dc.y;
          out[S + c] = (ddx * ddx + ddy * ddy < 16.0f) ? 0.0f : sT[r][c];
        }
      }
    }
    __syncthreads();
  }
}

extern "C" void kernel_launch(void* const* d_in, const int* in_sizes, int n_in,
                              void* d_out, int out_size, void* d_ws, size_t ws_size,
                              hipStream_t stream)
{
  const float* feat1 = (const float*)d_in[0];
  const float* feat2 = (const float*)d_in[1];
  const float* conf1 = (const float*)d_in[2];
  const float* aflow = (const float*)d_in[4];
  const int* pos = (const int*)d_in[5];
  const int* neg = (const int*)d_in[6];
  int P = in_sizes[5] / 2, NN = in_sizes[6] / 2;
  int NCOL = P + NN + NQ_;
  size_t GTOFF = (size_t)NQ_ * (size_t)NCOL;
  float* out = (float*)d_out;

  char* ws = (char*)d_ws;
  __hip_bfloat16* f1o = (__hip_bfloat16*)ws;                     // 1,843,200 B
  __hip_bfloat16* d3o = (__hip_bfloat16*)(ws + 1843200);         // 1,843,200 B
  float2* qxy = (float2*)(ws + 3686400);                         // 57,600 B
  float2* dxy = (float2*)(ws + 3744000);                         // 57,600 B
  __hip_bfloat16* f2t = (__hip_bfloat16*)(ws + 3801600);         // 134,217,728 B
  size_t needT = 3801600ull + (size_t)B_ * H_ * W_ * D_ * 2;
  bool useT = ws_size >= needT;

  float* omask  = out + 2 * GTOFF;
  float* oqconf = omask + NQ_;

  // zero the full gt region (posneg then writes cols 0..P+NN-1)
  gtzero_k<<<2048, 256, 0, stream>>>((f32x4*)(out + GTOFF), GTOFF / 4);

  if (useT){
    transpose_k<<<dim3(W_ / 64, H_, B_), 256, 0, stream>>>(feat2, f2t);
    prep_k<true><<<NQ_, 128, 0, stream>>>(feat1, feat2, f2t, conf1, aflow,
                                          f1o, d3o, qxy, dxy, omask, oqconf);
    posneg_k<true><<<NQ_, 256, 0, stream>>>(f1o, f2t, feat2, aflow, pos, neg,
                                            P, NN, out, NCOL, GTOFF);
  } else {
    prep_k<false><<<NQ_, 128, 0, stream>>>(feat1, feat2, f2t, conf1, aflow,
                                           f1o, d3o, qxy, dxy, omask, oqconf);
    posneg_k<false><<<NQ_, 256, 0, stream>>>(f1o, f2t, feat2, aflow, pos, neg,
                                             P, NN, out, NCOL, GTOFF);
  }
  gemm_k<<<dim3(NQ_ / 16, 4), 256, 0, stream>>>(f1o, d3o, qxy, dxy,
                                                out, NCOL, P + NN);
}

// Round 10
// 302.780 us; speedup vs baseline: 1.2759x; 1.1286x over previous
//
#include <hip/hip_runtime.h>
#include <hip/hip_bf16.h>
#include <stdint.h>

#define B_ 2
#define D_ 128
#define H_ 512
#define W_ 512
#define G_ 60
#define NQ_ 7200
#define BORDER_ 16
#define STEP_ 8

typedef __attribute__((ext_vector_type(8))) short short8;
typedef __attribute__((ext_vector_type(4))) float f32x4;
typedef __attribute__((ext_vector_type(4))) uint32_t u32x4;

__device__ __forceinline__ float bf_lo(uint32_t u){ return __builtin_bit_cast(float, u << 16); }
__device__ __forceinline__ float bf_hi(uint32_t u){ return __builtin_bit_cast(float, u & 0xffff0000u); }

__device__ __forceinline__ uint32_t pack2bf(float lo, float hi){
  uint16_t l = __builtin_bit_cast(uint16_t, __float2bfloat16(lo));
  uint16_t h = __builtin_bit_cast(uint16_t, __float2bfloat16(hi));
  return (uint32_t)l | ((uint32_t)h << 16);
}

// ---------------- gt region zero-fill (aligned full-line nt float4 stream) ----------------
__global__ __launch_bounds__(256) void gtzero_k(f32x4* __restrict__ gt, size_t n4){
  size_t i = (size_t)blockIdx.x * 256 + threadIdx.x;
  size_t stride = (size_t)gridDim.x * 256;
  f32x4 z = {0.f, 0.f, 0.f, 0.f};
  for (; i < n4; i += stride)
    __builtin_nontemporal_store(z, gt + i);
}

// ---------------- feat2 (B,D,H,W) f32 -> (B,H,W,D) bf16 ----------------
__global__ __launch_bounds__(256) void transpose_k(const float* __restrict__ src,
                                                   __hip_bfloat16* __restrict__ dst){
  __shared__ uint32_t lds2[64][65];
  int b = blockIdx.z, y = blockIdx.y, x0 = blockIdx.x * 64;
  int tid = threadIdx.x;
  size_t plane = (size_t)H_ * W_;

  int xq = tid & 15;        // x-quad (4 floats)
  int eg = tid >> 4;        // 0..15
  size_t base_in = (((size_t)b * D_) * H_ + y) * W_ + x0 + 4 * xq;
  #pragma unroll
  for (int it = 0; it < 4; ++it){
    int e = eg + 16 * it;   // d-pair 0..63
    f32x4 lo = __builtin_nontemporal_load(
        reinterpret_cast<const f32x4*>(src + base_in + (size_t)(2 * e) * plane));
    f32x4 hi = __builtin_nontemporal_load(
        reinterpret_cast<const f32x4*>(src + base_in + (size_t)(2 * e + 1) * plane));
    lds2[e][4 * xq + 0] = pack2bf(lo[0], hi[0]);
    lds2[e][4 * xq + 1] = pack2bf(lo[1], hi[1]);
    lds2[e][4 * xq + 2] = pack2bf(lo[2], hi[2]);
    lds2[e][4 * xq + 3] = pack2bf(lo[3], hi[3]);
  }
  __syncthreads();

  int eq = tid & 15;        // u32-quad within a pixel's 64-u32 row
  int xb = tid >> 4;        // 0..15
  size_t pixbase = (((size_t)b * H_ + y) * W_ + x0);
  #pragma unroll
  for (int it = 0; it < 4; ++it){
    int x = xb + 16 * it;
    u32x4 v;
    v[0] = lds2[4 * eq + 0][x];
    v[1] = lds2[4 * eq + 1][x];
    v[2] = lds2[4 * eq + 2][x];
    v[3] = lds2[4 * eq + 3][x];
    *reinterpret_cast<u32x4*>(dst + (pixbase + x) * D_ + 8 * eq) = v;
  }
}

// ---------------- per-query prep: f1, d3, xy tables, mask, qconf ----------------
template<bool USE_T>
__global__ __launch_bounds__(128) void prep_k(
    const float* __restrict__ feat1, const float* __restrict__ feat2,
    const __hip_bfloat16* __restrict__ f2t,
    const float* __restrict__ conf1, const float* __restrict__ aflow,
    __hip_bfloat16* __restrict__ f1o, __hip_bfloat16* __restrict__ d3o,
    float2* __restrict__ qxy, float2* __restrict__ dxy,
    float* __restrict__ omask, float* __restrict__ oqconf)
{
  int n = blockIdx.x;
  int b = n / (G_ * G_); int r = n % (G_ * G_);
  int iy = r / G_, ix = r % G_;
  int y1 = BORDER_ + iy * STEP_, x1 = BORDER_ + ix * STEP_;
  int tid = threadIdx.x;
  size_t pix = ((size_t)b * H_ + y1) * W_ + x1;
  if (tid < 64){
    int d = tid * 2;
    size_t o = (((size_t)b * D_ + d) * H_ + y1) * W_ + x1;
    float lo = feat1[o];
    float hi = feat1[o + (size_t)H_ * W_];
    *reinterpret_cast<uint32_t*>(f1o + (size_t)n * D_ + d) = pack2bf(lo, hi);
    if (tid == 0){
      float ax = aflow[(((size_t)b * 2 + 0) * H_ + y1) * W_ + x1];
      float ay = aflow[(((size_t)b * 2 + 1) * H_ + y1) * W_ + x1];
      int x2 = (int)(ax + 0.5f);   // trunc toward zero == astype(int32)
      int y2 = (int)(ay + 0.5f);
      omask[n] = (x2 >= 0 && y2 >= 0 && x2 < W_ && y2 < H_) ? 1.0f : 0.0f;
      oqconf[n] = conf1[pix];
      float bs = 512.0f * (float)b;
      qxy[n] = make_float2((float)x2 + bs, (float)y2 + bs);
      dxy[n] = make_float2((float)x1 + bs, (float)y1 + bs);
    }
  } else {
    int d = (tid - 64) * 2;
    uint32_t u;
    if (USE_T){
      u = *reinterpret_cast<const uint32_t*>(f2t + pix * D_ + d);
    } else {
      size_t o = (((size_t)b * D_ + d) * H_ + y1) * W_ + x1;
      u = pack2bf(feat2[o], feat2[o + (size_t)H_ * W_]);
    }
    *reinterpret_cast<uint32_t*>(d3o + (size_t)n * D_ + d) = u;
  }
}

// ---------------- pos/neg neighbor scores + gt cols 0..P+NN-1 ----------------
template<bool USE_T>
__global__ __launch_bounds__(256) void posneg_k(
    const __hip_bfloat16* __restrict__ f1o,
    const __hip_bfloat16* __restrict__ f2t,
    const float* __restrict__ feat2,
    const float* __restrict__ aflow,
    const int* __restrict__ pos, const int* __restrict__ neg,
    int P, int NN, float* __restrict__ out, int NCOL, size_t GTOFF)
{
  int n = blockIdx.x;
  int b = n / (G_ * G_); int r = n % (G_ * G_);
  int iy = r / G_, ix = r % G_;
  int y1 = BORDER_ + iy * STEP_, x1 = BORDER_ + ix * STEP_;
  int tid = threadIdx.x;
  int l16 = tid & 15, grp = tid >> 4;

  const uint4 av = *reinterpret_cast<const uint4*>(f1o + (size_t)n * D_ + l16 * 8);
  float a[8];
  a[0] = bf_lo(av.x); a[1] = bf_hi(av.x); a[2] = bf_lo(av.y); a[3] = bf_hi(av.y);
  a[4] = bf_lo(av.z); a[5] = bf_hi(av.z); a[6] = bf_lo(av.w); a[7] = bf_hi(av.w);

  float ax = aflow[(((size_t)b * 2 + 0) * H_ + y1) * W_ + x1];
  float ay = aflow[(((size_t)b * 2 + 1) * H_ + y1) * W_ + x1];
  int x2 = (int)(ax + 0.5f), y2 = (int)(ay + 0.5f);

  int NP = P + NN;
  for (int p0 = 0; p0 < NP; p0 += 16){
    int p = p0 + grp;
    float s = 0.0f;
    if (p < NP){
      int ox, oy;
      if (p < P){ ox = pos[p]; oy = pos[P + p]; }
      else      { ox = neg[p - P]; oy = neg[NN + p - P]; }
      int px = min(max(x2 + ox, 0), W_ - 1);
      int py = min(max(y2 + oy, 0), H_ - 1);
      if (USE_T){
        const uint4 v = *reinterpret_cast<const uint4*>(
            f2t + (((size_t)b * H_ + py) * W_ + px) * D_ + l16 * 8);
        s = a[0]*bf_lo(v.x) + a[1]*bf_hi(v.x) + a[2]*bf_lo(v.y) + a[3]*bf_hi(v.y)
          + a[4]*bf_lo(v.z) + a[5]*bf_hi(v.z) + a[6]*bf_lo(v.w) + a[7]*bf_hi(v.w);
      } else {
        size_t o = (((size_t)b * D_ + l16 * 8) * H_ + py) * W_ + px;
        #pragma unroll
        for (int j = 0; j < 8; ++j) s += a[j] * feat2[o + (size_t)j * H_ * W_];
      }
    }
    s += __shfl_xor(s, 1); s += __shfl_xor(s, 2);
    s += __shfl_xor(s, 4); s += __shfl_xor(s, 8);
    if (p < NP && l16 == 0){
      size_t idx = (size_t)n * NCOL + p;
      out[idx] = s;
      out[GTOFF + idx] = (p < P) ? 1.0f : 0.0f;   // gt zeroed by gtzero_k before
    }
  }
}

// ---- dscores GEMM, barrier-free wave-flow: 1 wave = 16 rows x 64(96) cols ----
// Each wave owns a private LDS tile; the fragment->row redistribution is
// wave-internal (ds_write -> lgkmcnt -> ds_read), so there is NO __syncthreads
// and no forced vmcnt(0) anywhere: stores from all waves stay in flight,
// mimicking the fill kernel's free-running store stream.
__global__ __launch_bounds__(256) void gemm_k(
    const __hip_bfloat16* __restrict__ f1o, const __hip_bfloat16* __restrict__ d3o,
    const float2* __restrict__ qxy, const float2* __restrict__ dxy,
    float* __restrict__ out, int NCOL, int CB)
{
  __shared__ float sT[4][16][100];
  int m0 = blockIdx.x * 16;
  int tid = threadIdx.x;
  int lane = tid & 63, wid = tid >> 6;
  int r16 = lane & 15, kg = lane >> 4;

  int c = blockIdx.y * 4 + wid;          // chunk 0..111 (wave-uniform)
  int cn0 = c * 64;
  int nc = (c == 111) ? 96 : 64;         // last chunk absorbs the 7200%64 tail

  // A fragments: 16 rows x K=128 in registers
  short8 af[4];
  #pragma unroll
  for (int ks = 0; ks < 4; ++ks)
    af[ks] = *reinterpret_cast<const short8*>(
        f1o + (size_t)(m0 + r16) * D_ + ks * 32 + kg * 8);

  f32x4 acc[6] = {};
  #pragma unroll
  for (int j = 0; j < 6; ++j){
    if (j * 16 < nc){                    // wave-uniform guard
      int nn = cn0 + j * 16 + r16;
      #pragma unroll
      for (int ks = 0; ks < 4; ++ks){
        short8 br = *reinterpret_cast<const short8*>(
            d3o + (size_t)nn * D_ + ks * 32 + kg * 8);
        acc[j] = __builtin_amdgcn_mfma_f32_16x16x32_bf16(br, af[ks], acc[j], 0, 0, 0);
      }
    }
  }

  // stage (wave-private): lane (r16,kg) holds rows r16, cols j*16+kg*4+t
  #pragma unroll
  for (int j = 0; j < 6; ++j)
    if (j * 16 < nc)
      *reinterpret_cast<f32x4*>(&sT[wid][r16][j * 16 + kg * 4]) = acc[j];

  float2 dcA = dxy[cn0 + lane];
  float2 dcB = dxy[cn0 + ((nc > 64) ? 64 + (lane & 31) : lane)];

  // drain: 16 rows, each a full-wave contiguous 256B cached store
  #pragma unroll
  for (int r = 0; r < 16; ++r){
    int m = m0 + r;
    float2 q = qxy[m];
    size_t S = (size_t)m * NCOL + CB + cn0;
    float v = sT[wid][r][lane];
    float ddx = q.x - dcA.x, ddy = q.y - dcA.y;
    out[S + lane] = (ddx * ddx + ddy * ddy < 16.0f) ? 0.0f : v;
    if (nc > 64 && lane < 32){
      float v2 = sT[wid][r][64 + lane];
      float ddx2 = q.x - dcB.x, ddy2 = q.y - dcB.y;
      out[S + 64 + lane] = (ddx2 * ddx2 + ddy2 * ddy2 < 16.0f) ? 0.0f : v2;
    }
  }
}

extern "C" void kernel_launch(void* const* d_in, const int* in_sizes, int n_in,
                              void* d_out, int out_size, void* d_ws, size_t ws_size,
                              hipStream_t stream)
{
  const float* feat1 = (const float*)d_in[0];
  const float* feat2 = (const float*)d_in[1];
  const float* conf1 = (const float*)d_in[2];
  const float* aflow = (const float*)d_in[4];
  const int* pos = (const int*)d_in[5];
  const int* neg = (const int*)d_in[6];
  int P = in_sizes[5] / 2, NN = in_sizes[6] / 2;
  int NCOL = P + NN + NQ_;
  size_t GTOFF = (size_t)NQ_ * (size_t)NCOL;
  float* out = (float*)d_out;

  char* ws = (char*)d_ws;
  __hip_bfloat16* f1o = (__hip_bfloat16*)ws;                     // 1,843,200 B
  __hip_bfloat16* d3o = (__hip_bfloat16*)(ws + 1843200);         // 1,843,200 B
  float2* qxy = (float2*)(ws + 3686400);                         // 57,600 B
  float2* dxy = (float2*)(ws + 3744000);                         // 57,600 B
  __hip_bfloat16* f2t = (__hip_bfloat16*)(ws + 3801600);         // 134,217,728 B
  size_t needT = 3801600ull + (size_t)B_ * H_ * W_ * D_ * 2;
  bool useT = ws_size >= needT;

  float* omask  = out + 2 * GTOFF;
  float* oqconf = omask + NQ_;

  // zero the full gt region (posneg then writes cols 0..P+NN-1)
  gtzero_k<<<2048, 256, 0, stream>>>((f32x4*)(out + GTOFF), GTOFF / 4);

  if (useT){
    transpose_k<<<dim3(W_ / 64, H_, B_), 256, 0, stream>>>(feat2, f2t);
    prep_k<true><<<NQ_, 128, 0, stream>>>(feat1, feat2, f2t, conf1, aflow,
                                          f1o, d3o, qxy, dxy, omask, oqconf);
    posneg_k<true><<<NQ_, 256, 0, stream>>>(f1o, f2t, feat2, aflow, pos, neg,
                                            P, NN, out, NCOL, GTOFF);
  } else {
    prep_k<false><<<NQ_, 128, 0, stream>>>(feat1, feat2, f2t, conf1, aflow,
                                           f1o, d3o, qxy, dxy, omask, oqconf);
    posneg_k<false><<<NQ_, 256, 0, stream>>>(f1o, f2t, feat2, aflow, pos, neg,
                                             P, NN, out, NCOL, GTOFF);
  }
  gemm_k<<<dim3(NQ_ / 16, 28), 256, 0, stream>>>(f1o, d3o, qxy, dxy,
                                                 out, NCOL, P + NN);
}

// Round 11
// 290.493 us; speedup vs baseline: 1.3299x; 1.0423x over previous
//
#include <hip/hip_runtime.h>
#include <hip/hip_bf16.h>
#include <stdint.h>

#define B_ 2
#define D_ 128
#define H_ 512
#define W_ 512
#define G_ 60
#define NQ_ 7200
#define BORDER_ 16
#define STEP_ 8

typedef __attribute__((ext_vector_type(8))) short short8;
typedef __attribute__((ext_vector_type(4))) float f32x4;
typedef __attribute__((ext_vector_type(4))) uint32_t u32x4;

__device__ __forceinline__ float bf_lo(uint32_t u){ return __builtin_bit_cast(float, u << 16); }
__device__ __forceinline__ float bf_hi(uint32_t u){ return __builtin_bit_cast(float, u & 0xffff0000u); }

__device__ __forceinline__ uint32_t pack2bf(float lo, float hi){
  uint16_t l = __builtin_bit_cast(uint16_t, __float2bfloat16(lo));
  uint16_t h = __builtin_bit_cast(uint16_t, __float2bfloat16(hi));
  return (uint32_t)l | ((uint32_t)h << 16);
}

// ---------------- gt region zero-fill (aligned full-line nt float4 stream) ----------------
__global__ __launch_bounds__(256) void gtzero_k(f32x4* __restrict__ gt, size_t n4){
  size_t i = (size_t)blockIdx.x * 256 + threadIdx.x;
  size_t stride = (size_t)gridDim.x * 256;
  f32x4 z = {0.f, 0.f, 0.f, 0.f};
  for (; i < n4; i += stride)
    __builtin_nontemporal_store(z, gt + i);
}

// ---------------- feat2 (B,D,H,W) f32 -> (B,H,W,D) bf16 ----------------
__global__ __launch_bounds__(256) void transpose_k(const float* __restrict__ src,
                                                   __hip_bfloat16* __restrict__ dst){
  __shared__ uint32_t lds2[64][65];
  int b = blockIdx.z, y = blockIdx.y, x0 = blockIdx.x * 64;
  int tid = threadIdx.x;
  size_t plane = (size_t)H_ * W_;

  int xq = tid & 15;        // x-quad (4 floats)
  int eg = tid >> 4;        // 0..15
  size_t base_in = (((size_t)b * D_) * H_ + y) * W_ + x0 + 4 * xq;
  #pragma unroll
  for (int it = 0; it < 4; ++it){
    int e = eg + 16 * it;   // d-pair 0..63
    f32x4 lo = __builtin_nontemporal_load(
        reinterpret_cast<const f32x4*>(src + base_in + (size_t)(2 * e) * plane));
    f32x4 hi = __builtin_nontemporal_load(
        reinterpret_cast<const f32x4*>(src + base_in + (size_t)(2 * e + 1) * plane));
    lds2[e][4 * xq + 0] = pack2bf(lo[0], hi[0]);
    lds2[e][4 * xq + 1] = pack2bf(lo[1], hi[1]);
    lds2[e][4 * xq + 2] = pack2bf(lo[2], hi[2]);
    lds2[e][4 * xq + 3] = pack2bf(lo[3], hi[3]);
  }
  __syncthreads();

  int eq = tid & 15;        // u32-quad within a pixel's 64-u32 row
  int xb = tid >> 4;        // 0..15
  size_t pixbase = (((size_t)b * H_ + y) * W_ + x0);
  #pragma unroll
  for (int it = 0; it < 4; ++it){
    int x = xb + 16 * it;
    u32x4 v;
    v[0] = lds2[4 * eq + 0][x];
    v[1] = lds2[4 * eq + 1][x];
    v[2] = lds2[4 * eq + 2][x];
    v[3] = lds2[4 * eq + 3][x];
    *reinterpret_cast<u32x4*>(dst + (pixbase + x) * D_ + 8 * eq) = v;
  }
}

// ---------------- per-query prep: f1, d3, xy tables, mask, qconf ----------------
template<bool USE_T>
__global__ __launch_bounds__(128) void prep_k(
    const float* __restrict__ feat1, const float* __restrict__ feat2,
    const __hip_bfloat16* __restrict__ f2t,
    const float* __restrict__ conf1, const float* __restrict__ aflow,
    __hip_bfloat16* __restrict__ f1o, __hip_bfloat16* __restrict__ d3o,
    float2* __restrict__ qxy, float2* __restrict__ dxy,
    float* __restrict__ omask, float* __restrict__ oqconf)
{
  int n = blockIdx.x;
  int b = n / (G_ * G_); int r = n % (G_ * G_);
  int iy = r / G_, ix = r % G_;
  int y1 = BORDER_ + iy * STEP_, x1 = BORDER_ + ix * STEP_;
  int tid = threadIdx.x;
  size_t pix = ((size_t)b * H_ + y1) * W_ + x1;
  if (tid < 64){
    int d = tid * 2;
    size_t o = (((size_t)b * D_ + d) * H_ + y1) * W_ + x1;
    float lo = feat1[o];
    float hi = feat1[o + (size_t)H_ * W_];
    *reinterpret_cast<uint32_t*>(f1o + (size_t)n * D_ + d) = pack2bf(lo, hi);
    if (tid == 0){
      float ax = aflow[(((size_t)b * 2 + 0) * H_ + y1) * W_ + x1];
      float ay = aflow[(((size_t)b * 2 + 1) * H_ + y1) * W_ + x1];
      int x2 = (int)(ax + 0.5f);   // trunc toward zero == astype(int32)
      int y2 = (int)(ay + 0.5f);
      omask[n] = (x2 >= 0 && y2 >= 0 && x2 < W_ && y2 < H_) ? 1.0f : 0.0f;
      oqconf[n] = conf1[pix];
      float bs = 512.0f * (float)b;
      qxy[n] = make_float2((float)x2 + bs, (float)y2 + bs);
      dxy[n] = make_float2((float)x1 + bs, (float)y1 + bs);
    }
  } else {
    int d = (tid - 64) * 2;
    uint32_t u;
    if (USE_T){
      u = *reinterpret_cast<const uint32_t*>(f2t + pix * D_ + d);
    } else {
      size_t o = (((size_t)b * D_ + d) * H_ + y1) * W_ + x1;
      u = pack2bf(feat2[o], feat2[o + (size_t)H_ * W_]);
    }
    *reinterpret_cast<uint32_t*>(d3o + (size_t)n * D_ + d) = u;
  }
}

// ---------------- pos/neg neighbor scores + gt cols 0..P+NN-1 ----------------
// Runs AFTER gemm: its cached partial-line writes at the col-116/117 boundary
// must follow gemm's nt writes so the L2 fetch sees the post-nt HBM data.
template<bool USE_T>
__global__ __launch_bounds__(256) void posneg_k(
    const __hip_bfloat16* __restrict__ f1o,
    const __hip_bfloat16* __restrict__ f2t,
    const float* __restrict__ feat2,
    const float* __restrict__ aflow,
    const int* __restrict__ pos, const int* __restrict__ neg,
    int P, int NN, float* __restrict__ out, int NCOL, size_t GTOFF)
{
  int n = blockIdx.x;
  int b = n / (G_ * G_); int r = n % (G_ * G_);
  int iy = r / G_, ix = r % G_;
  int y1 = BORDER_ + iy * STEP_, x1 = BORDER_ + ix * STEP_;
  int tid = threadIdx.x;
  int l16 = tid & 15, grp = tid >> 4;

  const uint4 av = *reinterpret_cast<const uint4*>(f1o + (size_t)n * D_ + l16 * 8);
  float a[8];
  a[0] = bf_lo(av.x); a[1] = bf_hi(av.x); a[2] = bf_lo(av.y); a[3] = bf_hi(av.y);
  a[4] = bf_lo(av.z); a[5] = bf_hi(av.z); a[6] = bf_lo(av.w); a[7] = bf_hi(av.w);

  float ax = aflow[(((size_t)b * 2 + 0) * H_ + y1) * W_ + x1];
  float ay = aflow[(((size_t)b * 2 + 1) * H_ + y1) * W_ + x1];
  int x2 = (int)(ax + 0.5f), y2 = (int)(ay + 0.5f);

  int NP = P + NN;
  for (int p0 = 0; p0 < NP; p0 += 16){
    int p = p0 + grp;
    float s = 0.0f;
    if (p < NP){
      int ox, oy;
      if (p < P){ ox = pos[p]; oy = pos[P + p]; }
      else      { ox = neg[p - P]; oy = neg[NN + p - P]; }
      int px = min(max(x2 + ox, 0), W_ - 1);
      int py = min(max(y2 + oy, 0), H_ - 1);
      if (USE_T){
        const uint4 v = *reinterpret_cast<const uint4*>(
            f2t + (((size_t)b * H_ + py) * W_ + px) * D_ + l16 * 8);
        s = a[0]*bf_lo(v.x) + a[1]*bf_hi(v.x) + a[2]*bf_lo(v.y) + a[3]*bf_hi(v.y)
          + a[4]*bf_lo(v.z) + a[5]*bf_hi(v.z) + a[6]*bf_lo(v.w) + a[7]*bf_hi(v.w);
      } else {
        size_t o = (((size_t)b * D_ + l16 * 8) * H_ + py) * W_ + px;
        #pragma unroll
        for (int j = 0; j < 8; ++j) s += a[j] * feat2[o + (size_t)j * H_ * W_];
      }
    }
    s += __shfl_xor(s, 1); s += __shfl_xor(s, 2);
    s += __shfl_xor(s, 4); s += __shfl_xor(s, 8);
    if (p < NP && l16 == 0){
      size_t idx = (size_t)n * NCOL + p;
      out[idx] = s;
      out[GTOFF + idx] = (p < P) ? 1.0f : 0.0f;   // gt zeroed by gtzero_k before
    }
  }
}

// ---- dscores GEMM, barrier-free wave-flow + NONTEMPORAL drain ----
// Identical structure to R10; only the drain stores changed cached -> nt.
// Theory: cached streaming stores cap at ~1.3 TB/s (L2 dirty-eviction path);
// nt bypasses allocation (gtzero proves 6.4 TB/s on this same buffer).
__global__ __launch_bounds__(256) void gemm_k(
    const __hip_bfloat16* __restrict__ f1o, const __hip_bfloat16* __restrict__ d3o,
    const float2* __restrict__ qxy, const float2* __restrict__ dxy,
    float* __restrict__ out, int NCOL, int CB)
{
  __shared__ float sT[4][16][100];
  int m0 = blockIdx.x * 16;
  int tid = threadIdx.x;
  int lane = tid & 63, wid = tid >> 6;
  int r16 = lane & 15, kg = lane >> 4;

  int c = blockIdx.y * 4 + wid;          // chunk 0..111 (wave-uniform)
  int cn0 = c * 64;
  int nc = (c == 111) ? 96 : 64;         // last chunk absorbs the 7200%64 tail

  // A fragments: 16 rows x K=128 in registers
  short8 af[4];
  #pragma unroll
  for (int ks = 0; ks < 4; ++ks)
    af[ks] = *reinterpret_cast<const short8*>(
        f1o + (size_t)(m0 + r16) * D_ + ks * 32 + kg * 8);

  f32x4 acc[6] = {};
  #pragma unroll
  for (int j = 0; j < 6; ++j){
    if (j * 16 < nc){                    // wave-uniform guard
      int nn = cn0 + j * 16 + r16;
      #pragma unroll
      for (int ks = 0; ks < 4; ++ks){
        short8 br = *reinterpret_cast<const short8*>(
            d3o + (size_t)nn * D_ + ks * 32 + kg * 8);
        acc[j] = __builtin_amdgcn_mfma_f32_16x16x32_bf16(br, af[ks], acc[j], 0, 0, 0);
      }
    }
  }

  // stage (wave-private): lane (r16,kg) holds rows r16, cols j*16+kg*4+t
  #pragma unroll
  for (int j = 0; j < 6; ++j)
    if (j * 16 < nc)
      *reinterpret_cast<f32x4*>(&sT[wid][r16][j * 16 + kg * 4]) = acc[j];

  float2 dcA = dxy[cn0 + lane];
  float2 dcB = dxy[cn0 + ((nc > 64) ? 64 + (lane & 31) : lane)];

  // drain: 16 rows, each a full-wave contiguous 256B nt store
  size_t S = (size_t)m0 * NCOL + CB + cn0;
  #pragma unroll
  for (int r = 0; r < 16; ++r, S += NCOL){
    float2 q = qxy[m0 + r];
    float v = sT[wid][r][lane];
    float ddx = q.x - dcA.x, ddy = q.y - dcA.y;
    float val = (ddx * ddx + ddy * ddy < 16.0f) ? 0.0f : v;
    __builtin_nontemporal_store(val, out + S + lane);
    if (nc > 64 && lane < 32){
      float v2 = sT[wid][r][64 + lane];
      float ddx2 = q.x - dcB.x, ddy2 = q.y - dcB.y;
      float val2 = (ddx2 * ddx2 + ddy2 * ddy2 < 16.0f) ? 0.0f : v2;
      __builtin_nontemporal_store(val2, out + S + 64 + lane);
    }
  }
}

extern "C" void kernel_launch(void* const* d_in, const int* in_sizes, int n_in,
                              void* d_out, int out_size, void* d_ws, size_t ws_size,
                              hipStream_t stream)
{
  const float* feat1 = (const float*)d_in[0];
  const float* feat2 = (const float*)d_in[1];
  const float* conf1 = (const float*)d_in[2];
  const float* aflow = (const float*)d_in[4];
  const int* pos = (const int*)d_in[5];
  const int* neg = (const int*)d_in[6];
  int P = in_sizes[5] / 2, NN = in_sizes[6] / 2;
  int NCOL = P + NN + NQ_;
  size_t GTOFF = (size_t)NQ_ * (size_t)NCOL;
  float* out = (float*)d_out;

  char* ws = (char*)d_ws;
  __hip_bfloat16* f1o = (__hip_bfloat16*)ws;                     // 1,843,200 B
  __hip_bfloat16* d3o = (__hip_bfloat16*)(ws + 1843200);         // 1,843,200 B
  float2* qxy = (float2*)(ws + 3686400);                         // 57,600 B
  float2* dxy = (float2*)(ws + 3744000);                         // 57,600 B
  __hip_bfloat16* f2t = (__hip_bfloat16*)(ws + 3801600);         // 134,217,728 B
  size_t needT = 3801600ull + (size_t)B_ * H_ * W_ * D_ * 2;
  bool useT = ws_size >= needT;

  float* omask  = out + 2 * GTOFF;
  float* oqconf = omask + NQ_;

  // zero the full gt region (posneg then writes cols 0..P+NN-1)
  gtzero_k<<<2048, 256, 0, stream>>>((f32x4*)(out + GTOFF), GTOFF / 4);

  if (useT){
    transpose_k<<<dim3(W_ / 64, H_, B_), 256, 0, stream>>>(feat2, f2t);
    prep_k<true><<<NQ_, 128, 0, stream>>>(feat1, feat2, f2t, conf1, aflow,
                                          f1o, d3o, qxy, dxy, omask, oqconf);
    gemm_k<<<dim3(NQ_ / 16, 28), 256, 0, stream>>>(f1o, d3o, qxy, dxy,
                                                   out, NCOL, P + NN);
    posneg_k<true><<<NQ_, 256, 0, stream>>>(f1o, f2t, feat2, aflow, pos, neg,
                                            P, NN, out, NCOL, GTOFF);
  } else {
    prep_k<false><<<NQ_, 128, 0, stream>>>(feat1, feat2, f2t, conf1, aflow,
                                           f1o, d3o, qxy, dxy, omask, oqconf);
    gemm_k<<<dim3(NQ_ / 16, 28), 256, 0, stream>>>(f1o, d3o, qxy, dxy,
                                                   out, NCOL, P + NN);
    posneg_k<false><<<NQ_, 256, 0, stream>>>(f1o, f2t, feat2, aflow, pos, neg,
                                             P, NN, out, NCOL, GTOFF);
  }
}